// Round 1
// baseline (350.112 us; speedup 1.0000x reference)
//
#include <hip/hip_runtime.h>
#include <math.h>

#define DIM 128
#define NATOMS 8192
#define LPROT 8192
#define CAP 64
#define NF (NATOMS*DIM)

// ---------------- gather: out[r] = emb[idx[r]] ----------------
__global__ void k_gather(const int* __restrict__ idx, const float* __restrict__ emb,
                         float* __restrict__ out, int n) {
  int i = blockIdx.x * blockDim.x + threadIdx.x;
  int row = i >> 5, c4 = i & 31;
  if (row < n) {
    const float4* s = (const float4*)(emb + (size_t)idx[row] * DIM);
    ((float4*)(out + (size_t)row * DIM))[c4] = s[c4];
  }
}

// ---------------- 128x128 transpose (batched) ----------------
__global__ void k_transpose128(const float* __restrict__ in, float* __restrict__ out) {
  __shared__ float tile[32][33];
  int b = blockIdx.x;
  int m = b >> 4; int t = b & 15;
  int tx = t & 3, ty = t >> 2;
  const float* src = in + m * (DIM * DIM);
  float* dst = out + m * (DIM * DIM);
  int x = tx * 32 + threadIdx.x;
  for (int i = threadIdx.y; i < 32; i += 8)
    tile[i][threadIdx.x] = src[(ty * 32 + i) * DIM + x];
  __syncthreads();
  int xo = ty * 32 + threadIdx.x;
  for (int i = threadIdx.y; i < 32; i += 8)
    dst[(tx * 32 + i) * DIM + xo] = tile[threadIdx.x][i];
}

// ---------------- build ELL from dense binary adjacency ----------------
// one wave per row; ordered (within each mod-4 pass) ballot-compaction
__global__ void k_build_ell(const float* __restrict__ adj, int* __restrict__ ell,
                            int* __restrict__ cnt) {
  int wv = threadIdx.x >> 6, lane = threadIdx.x & 63;
  int row = blockIdx.x * 4 + wv;
  const float4* rp = (const float4*)(adj + (size_t)row * NATOMS);
  int* er = ell + (size_t)row * CAP;
  int c = 0;
  for (int it = 0; it < NATOMS / 256; ++it) {
    float4 v = rp[(size_t)it * 64 + lane];
    float f[4] = {v.x, v.y, v.z, v.w};
    #pragma unroll
    for (int j = 0; j < 4; ++j) {
      bool nz = (f[j] != 0.0f);
      unsigned long long m = __ballot(nz);
      if (nz) {
        int pos = c + __popcll(m & ((1ull << lane) - 1ull));
        if (pos < CAP) er[pos] = it * 256 + lane * 4 + j;
      }
      c += __popcll(m);
    }
  }
  if (lane == 0) cnt[row] = c > CAP ? CAP : c;
}

// ---------------- C = relu(A @ W^T + b), WT pre-transposed [k][j] ----------------
// 128 threads, 32 rows/block, 4x8 register tile, W staged in two 64-row halves
__global__ __launch_bounds__(128) void k_gemm_relu(const float* __restrict__ A,
    const float* __restrict__ WT, const float* __restrict__ bias,
    float* __restrict__ C) {
  __shared__ float As[32 * 132];
  __shared__ float Ws[64 * 128];
  int tid = threadIdx.x;
  int r0 = (tid >> 4) * 4;
  int j0 = (tid & 15) * 8;
  size_t rowBase = (size_t)blockIdx.x * 32;

  for (int i = tid; i < 32 * 32; i += 128) {
    int r = i >> 5, c4 = i & 31;
    *(float4*)&As[r * 132 + c4 * 4] = *(const float4*)&A[(rowBase + r) * DIM + c4 * 4];
  }
  float acc[4][8];
  {
    float4 b0 = *(const float4*)&bias[j0];
    float4 b1 = *(const float4*)&bias[j0 + 4];
    float bv[8] = {b0.x, b0.y, b0.z, b0.w, b1.x, b1.y, b1.z, b1.w};
    #pragma unroll
    for (int ri = 0; ri < 4; ++ri)
      #pragma unroll
      for (int jj = 0; jj < 8; ++jj) acc[ri][jj] = bv[jj];
  }
  #pragma unroll
  for (int half = 0; half < 2; ++half) {
    __syncthreads();
    for (int i = tid; i < 64 * 32; i += 128)
      *(float4*)&Ws[i * 4] = *(const float4*)&WT[(size_t)half * 64 * DIM + i * 4];
    __syncthreads();
    for (int k4 = 0; k4 < 16; ++k4) {
      float as[4][4];
      #pragma unroll
      for (int ri = 0; ri < 4; ++ri)
        *(float4*)as[ri] = *(float4*)&As[(r0 + ri) * 132 + half * 64 + k4 * 4];
      #pragma unroll
      for (int i = 0; i < 4; ++i) {
        float4 wa = *(float4*)&Ws[(k4 * 4 + i) * DIM + j0];
        float4 wb = *(float4*)&Ws[(k4 * 4 + i) * DIM + j0 + 4];
        float wv[8] = {wa.x, wa.y, wa.z, wa.w, wb.x, wb.y, wb.z, wb.w};
        #pragma unroll
        for (int ri = 0; ri < 4; ++ri)
          #pragma unroll
          for (int jj = 0; jj < 8; ++jj)
            acc[ri][jj] += as[ri][i] * wv[jj];
      }
    }
  }
  #pragma unroll
  for (int ri = 0; ri < 4; ++ri) {
    float4 o0, o1;
    o0.x = fmaxf(acc[ri][0], 0.f); o0.y = fmaxf(acc[ri][1], 0.f);
    o0.z = fmaxf(acc[ri][2], 0.f); o0.w = fmaxf(acc[ri][3], 0.f);
    o1.x = fmaxf(acc[ri][4], 0.f); o1.y = fmaxf(acc[ri][5], 0.f);
    o1.z = fmaxf(acc[ri][6], 0.f); o1.w = fmaxf(acc[ri][7], 0.f);
    *(float4*)&C[(rowBase + r0 + ri) * DIM + j0]     = o0;
    *(float4*)&C[(rowBase + r0 + ri) * DIM + j0 + 4] = o1;
  }
}

// ---------------- xs[row] += sum_{j in nbr(row)} hs[j] ----------------
__global__ void k_spmv_add(const int* __restrict__ ell, const int* __restrict__ cnt,
                           const float* __restrict__ hs, float* __restrict__ xs) {
  int wv = threadIdx.x >> 6, lane = threadIdx.x & 63;
  int row = blockIdx.x * 4 + wv;
  int n = cnt[row];
  const int* er = ell + (size_t)row * CAP;
  float2 acc = *(const float2*)&xs[(size_t)row * DIM + lane * 2];
  for (int t = 0; t < n; ++t) {
    int j = er[t];
    float2 h = *(const float2*)&hs[(size_t)j * DIM + lane * 2];
    acc.x += h.x; acc.y += h.y;
  }
  *(float2*)&xs[(size_t)row * DIM + lane * 2] = acc;
}

// ---------------- column sums ----------------
__global__ void k_colsum_part(const float* __restrict__ in, float* __restrict__ part) {
  int c = threadIdx.x & 127, h = threadIdx.x >> 7;
  size_t r0 = (size_t)blockIdx.x * 128;
  float s = 0.f;
  for (int t = 0; t < 64; ++t) s += in[(r0 + h + 2 * t) * DIM + c];
  __shared__ float buf[DIM];
  if (h) buf[c] = s;
  __syncthreads();
  if (!h) part[blockIdx.x * DIM + c] = s + buf[c];
}

__global__ void k_colsum_final(const float* __restrict__ part, float* __restrict__ o) {
  int c = threadIdx.x;
  float s = 0.f;
  for (int b = 0; b < 64; ++b) s += part[b * DIM + c];
  o[c] = s;
}

// ---------------- x_{i+1} = relu(x_i @ Wa^T + ba), i=0..2 ----------------
__global__ void k_xchain(const float* __restrict__ xc, const float* __restrict__ WaT,
                         const float* __restrict__ ba, float* __restrict__ xall) {
  __shared__ float xb[DIM];
  int j = threadIdx.x;
  xb[j] = xc[j];
  float bj = ba[j];
  for (int i = 0; i < 3; ++i) {
    __syncthreads();
    float acc = bj;
    for (int k = 0; k < DIM; ++k) acc += xb[k] * WaT[k * DIM + j];
    acc = fmaxf(acc, 0.f);
    __syncthreads();
    xb[j] = acc;
    xall[i * DIM + j] = acc;
  }
}

// ---------------- 23x23 "image" conv over [L, DIM], zero-padded both dims ----------------
__global__ __launch_bounds__(256) void k_conv23(const float* __restrict__ in,
    const float* __restrict__ cw, const float* __restrict__ cb,
    float* __restrict__ out) {
  __shared__ float t[54][156];
  __shared__ float wl[23][24];
  int tid = threadIdx.x;
  int l0 = blockIdx.x * 32;
  for (int idx = tid; idx < 529; idx += 256)
    wl[idx / 23][idx % 23] = cw[idx];
  for (int idx = tid; idx < 54 * 150; idx += 256) {
    int ll = idx / 150, dd = idx % 150;
    int gl = l0 - 11 + ll, gd = dd - 11;
    float v = 0.f;
    if (gl >= 0 && gl < LPROT && gd >= 0 && gd < DIM)
      v = in[(size_t)gl * DIM + gd];
    t[ll][dd] = v;
  }
  __syncthreads();
  int lo = tid & 31, dg = tid >> 5;
  int d0 = dg * 16;
  float acc[16];
  #pragma unroll
  for (int m = 0; m < 16; ++m) acc[m] = 0.f;
  for (int a = 0; a < 23; ++a) {
    float r[40];
    #pragma unroll
    for (int q = 0; q < 9; ++q)
      *(float4*)&r[4 * q] = *(float4*)&t[lo + a][d0 + 4 * q];
    r[36] = t[lo + a][d0 + 36];
    r[37] = t[lo + a][d0 + 37];
    float w[24];
    #pragma unroll
    for (int q = 0; q < 6; ++q)
      *(float4*)&w[4 * q] = *(float4*)&wl[a][4 * q];
    #pragma unroll
    for (int b = 0; b < 23; ++b)
      #pragma unroll
      for (int m = 0; m < 16; ++m)
        acc[m] += r[b + m] * w[b];
  }
  float bias = cb[0];
  #pragma unroll
  for (int m8 = 0; m8 < 4; ++m8) {
    float4 o;
    o.x = fmaxf(acc[m8 * 4 + 0] + bias, 0.f);
    o.y = fmaxf(acc[m8 * 4 + 1] + bias, 0.f);
    o.z = fmaxf(acc[m8 * 4 + 2] + bias, 0.f);
    o.w = fmaxf(acc[m8 * 4 + 3] + bias, 0.f);
    *(float4*)&out[(size_t)(l0 + lo) * DIM + d0 + m8 * 4] = o;
  }
}

// ---------------- xsp[l] = tanh(dot(x, hs[l])) * hs[l] ----------------
__global__ void k_attn(const float* __restrict__ x, const float* __restrict__ hs,
                       float* __restrict__ xsp) {
  int wv = threadIdx.x >> 6, lane = threadIdx.x & 63;
  int l = blockIdx.x * 4 + wv;
  float2 h = *(const float2*)&hs[(size_t)l * DIM + 2 * lane];
  float x0 = x[2 * lane], x1 = x[2 * lane + 1];
  float p = x0 * h.x + x1 * h.y;
  #pragma unroll
  for (int s = 32; s > 0; s >>= 1) p += __shfl_xor(p, s, 64);
  float w = tanhf(p);
  float2 o; o.x = w * h.x; o.y = w * h.y;
  *(float2*)&xsp[(size_t)l * DIM + 2 * lane] = o;
}

// ---------------- final: softmax([xc|xp] @ Wo^T + bo) ----------------
__global__ void k_final(const float* __restrict__ xc, const float* __restrict__ xp,
                        const float* __restrict__ Wo, const float* __restrict__ bo,
                        float* __restrict__ out) {
  int t = threadIdx.x;
  float y = (t < DIM) ? xc[t] : xp[t - DIM];
  float p0 = y * Wo[t];
  float p1 = y * Wo[256 + t];
  #pragma unroll
  for (int s = 32; s > 0; s >>= 1) {
    p0 += __shfl_xor(p0, s, 64);
    p1 += __shfl_xor(p1, s, 64);
  }
  __shared__ float r0[4], r1[4];
  int wv = t >> 6;
  if ((t & 63) == 0) { r0[wv] = p0; r1[wv] = p1; }
  __syncthreads();
  if (t == 0) {
    float l0 = r0[0] + r0[1] + r0[2] + r0[3] + bo[0];
    float l1 = r1[0] + r1[1] + r1[2] + r1[3] + bo[1];
    float m = fmaxf(l0, l1);
    float e0 = expf(l0 - m), e1 = expf(l1 - m);
    float s = e0 + e1;
    out[0] = e0 / s;
    out[1] = e1 / s;
  }
}

extern "C" void kernel_launch(void* const* d_in, const int* in_sizes, int n_in,
                              void* d_out, int out_size, void* d_ws, size_t ws_size,
                              hipStream_t stream) {
  const int*   fp     = (const int*)d_in[0];
  const int*   words  = (const int*)d_in[1];
  const float* adj    = (const float*)d_in[2];
  const float* emb_fp = (const float*)d_in[3];
  const float* emb_w  = (const float*)d_in[4];
  const float* Wg     = (const float*)d_in[5];
  const float* bg     = (const float*)d_in[6];
  const float* cw     = (const float*)d_in[7];
  const float* cb     = (const float*)d_in[8];
  const float* Wa     = (const float*)d_in[9];
  const float* ba     = (const float*)d_in[10];
  const float* Wo     = (const float*)d_in[11];
  const float* bo     = (const float*)d_in[12];
  float* out = (float*)d_out;

  float* ws   = (float*)d_ws;
  float* xs   = ws;                       // [8192,128]
  float* hsb  = ws + (size_t)NF;          // [8192,128]
  float* xsp  = ws + 2 * (size_t)NF;      // [8192,128]
  float* hs2  = ws + 3 * (size_t)NF;      // [8192,128]
  int*   ell  = (int*)(ws + 4 * (size_t)NF);
  int*   cnt  = ell + (size_t)NATOMS * CAP;
  float* part = (float*)(cnt + NATOMS);   // [64,128]
  float* xc   = part + 64 * DIM;          // [128]
  float* xp   = xc + DIM;                 // [128]
  float* xall = xp + DIM;                 // [3,128]
  float* WgT  = xall + 3 * DIM;           // [3,128,128]
  float* WaT  = WgT + 3 * DIM * DIM;      // [128,128]

  k_gather<<<dim3(NATOMS * 32 / 256), 256, 0, stream>>>(fp, emb_fp, xs, NATOMS);
  k_gather<<<dim3(LPROT * 32 / 256), 256, 0, stream>>>(words, emb_w, xsp, LPROT);
  k_transpose128<<<dim3(48), dim3(32, 8), 0, stream>>>(Wg, WgT);
  k_transpose128<<<dim3(16), dim3(32, 8), 0, stream>>>(Wa, WaT);
  k_build_ell<<<dim3(NATOMS / 4), 256, 0, stream>>>(adj, ell, cnt);

  for (int i = 0; i < 3; ++i) {
    k_gemm_relu<<<dim3(NATOMS / 32), 128, 0, stream>>>(xs, WgT + i * DIM * DIM, bg + i * DIM, hsb);
    k_spmv_add<<<dim3(NATOMS / 4), 256, 0, stream>>>(ell, cnt, hsb, xs);
  }
  k_colsum_part<<<dim3(64), 256, 0, stream>>>(xs, part);
  k_colsum_final<<<dim3(1), DIM, 0, stream>>>(part, xc);
  k_xchain<<<dim3(1), DIM, 0, stream>>>(xc, WaT, ba, xall);

  for (int i = 0; i < 3; ++i) {
    k_conv23<<<dim3(LPROT / 32), 256, 0, stream>>>(xsp, cw + i * 529, cb + i, hsb);
    k_gemm_relu<<<dim3(LPROT / 32), 128, 0, stream>>>(hsb, WaT, ba, hs2);
    k_attn<<<dim3(LPROT / 4), 256, 0, stream>>>(xall + i * DIM, hs2, xsp);
  }
  k_colsum_part<<<dim3(64), 256, 0, stream>>>(xsp, part);
  k_colsum_final<<<dim3(1), DIM, 0, stream>>>(part, xp);
  k_final<<<dim3(1), 256, 0, stream>>>(xc, xp, Wo, bo, out);
}